// Round 6
// baseline (111.161 us; speedup 1.0000x reference)
//
#include <hip/hip_runtime.h>
#include <hip/hip_bf16.h>
#include <stdint.h>

#define B_N 8192
#define D_N 1024
#define K_N 8
#define H_N 2048

#define BM 288
#define BN 256
#define NBLK 256
// Half-step (BK=32) buffers: A 288x32x2 = 18432 B + B 256x32x2 = 16384 B = 34816 B.
// 4-buffer rotation: 4 x 34816 = 139264.
//   ro=139264(1152) pll=140416(4608)  total 145024 (<=163840), 1 block/CU.
#define ABYTES_HS 18432
#define HSB 34816
#define RO_OFF 139264
#define PLL_OFF 140416
#define GEMM_LDS 145024

typedef unsigned int u32;
typedef unsigned short u16;
typedef __attribute__((ext_vector_type(8))) short short8;
typedef __attribute__((ext_vector_type(4))) float float4v;

struct __align__(8) us4 { u16 x, y, z, w; };

__device__ __forceinline__ u16 f2bf(float f) {
    union { float f; u32 u; } v; v.f = f;
    u32 u = v.u;
    u32 r = (u + 0x7fffu + ((u >> 16) & 1u)) >> 16;
    return (u16)r;
}

__device__ __forceinline__ float fast_tanh(float x) {
    float t = __expf(2.0f * x);
    return 1.0f - 2.0f * __builtin_amdgcn_rcpf(t + 1.0f);
}

__device__ __forceinline__ void async_copy16(void* lds, const void* g) {
    __builtin_amdgcn_global_load_lds(
        (const __attribute__((address_space(1))) void*)g,
        (__attribute__((address_space(3))) void*)lds, 16, 0, 0);
}

// ---------------- routing: f64 argmin + x->bf16 (NO atomics) ----------------
__global__ void route_kernel(const float* __restrict__ x,
                             const float* __restrict__ cent,
                             u16* __restrict__ xbf,
                             int* __restrict__ cluster,
                             u32* __restrict__ counts) {
    int tid = threadIdx.x;
    if (blockIdx.x == 0 && tid < K_N) counts[tid * 32] = 0;  // zero strided counters
    int wave = tid >> 6, lane = tid & 63;
    int b = blockIdx.x * 4 + wave;
    const float* xr = x + (size_t)b * D_N;

    float4 xv[4];
#pragma unroll
    for (int i = 0; i < 4; ++i)
        xv[i] = *(const float4*)(xr + i * 256 + lane * 4);

#pragma unroll
    for (int i = 0; i < 4; ++i) {
        us4 o;
        o.x = f2bf(xv[i].x); o.y = f2bf(xv[i].y);
        o.z = f2bf(xv[i].z); o.w = f2bf(xv[i].w);
        *(us4*)(xbf + (size_t)b * D_N + i * 256 + lane * 4) = o;
    }

    double acc[K_N];
#pragma unroll
    for (int k = 0; k < K_N; ++k) {
        const float* cr = cent + k * D_N;
        double s = 0.0;
#pragma unroll
        for (int i = 0; i < 4; ++i) {
            float4 cv = *(const float4*)(cr + i * 256 + lane * 4);
            double d0 = (double)xv[i].x - (double)cv.x; s += d0 * d0;
            double d1 = (double)xv[i].y - (double)cv.y; s += d1 * d1;
            double d2 = (double)xv[i].z - (double)cv.z; s += d2 * d2;
            double d3 = (double)xv[i].w - (double)cv.w; s += d3 * d3;
        }
        acc[k] = s;
    }
#pragma unroll
    for (int k = 0; k < K_N; ++k) {
        double v = acc[k];
        for (int off = 32; off; off >>= 1) v += __shfl_down(v, off);
        acc[k] = v;
    }
    if (lane == 0) {
        int best = 0; double bv = acc[0];
#pragma unroll
        for (int k = 1; k < K_N; ++k)
            if (acc[k] < bv) { bv = acc[k]; best = k; }
        cluster[b] = best;
    }
}

// ---------------- parallel binning: 32 blocks, ballot-rank + block reserve ----------------
__global__ void scatter_kernel(const int* __restrict__ cluster,
                               u32* __restrict__ counts,
                               u32* __restrict__ idxl) {
    __shared__ u32 wcnt[4][K_N];
    __shared__ u32 gb[K_N];
    int tid = threadIdx.x;
    int b = blockIdx.x * 256 + tid;
    int lane = tid & 63, wid = tid >> 6;
    int cl = cluster[b];
    unsigned long long lower = (1ull << lane) - 1ull;
    u32 rank = 0;
#pragma unroll
    for (int k = 0; k < K_N; ++k) {
        unsigned long long mk = __ballot(cl == k);
        if (k == cl) rank = (u32)__popcll(mk & lower);
        if (lane == 0) wcnt[wid][k] = (u32)__popcll(mk);
    }
    __syncthreads();
    if (tid < K_N) {
        u32 tot = wcnt[0][tid] + wcnt[1][tid] + wcnt[2][tid] + wcnt[3][tid];
        gb[tid] = atomicAdd(&counts[tid * 32], tot);   // reserve range (order-free)
    }
    __syncthreads();
    u32 woff = 0;
    if (wid > 0) woff += wcnt[0][cl];
    if (wid > 1) woff += wcnt[1][cl];
    if (wid > 2) woff += wcnt[2][cl];
    idxl[(size_t)cl * B_N + gb[cl] + woff + rank] = (u32)b;
}

// ---------------- W1[k,d,h] f32 -> W1t[k,h,d] bf16 (vectorized) ----------------
__global__ void w1t_kernel(const float* __restrict__ w1, u16* __restrict__ w1t) {
    __shared__ float ts[64][65];
    int tid = threadIdx.x;
    int h0 = blockIdx.x * 64, d0 = blockIdx.y * 64, k = blockIdx.z;
    const float* src = w1 + ((size_t)k * D_N + d0) * H_N + h0;
#pragma unroll
    for (int i = 0; i < 4; ++i) {
        int q = i * 256 + tid;
        int r = q >> 4, c4 = (q & 15) * 4;          // d-row, h-col4
        float4 v = *(const float4*)(src + (size_t)r * H_N + c4);
        ts[c4 + 0][r] = v.x; ts[c4 + 1][r] = v.y;
        ts[c4 + 2][r] = v.z; ts[c4 + 3][r] = v.w;
    }
    __syncthreads();
    u16* dst = w1t + ((size_t)k * H_N + h0) * D_N + d0;
#pragma unroll
    for (int i = 0; i < 4; ++i) {
        int q = i * 256 + tid;
        int hr = q >> 4, d4 = (q & 15) * 4;         // h-row, d-col4
        us4 o;
        o.x = f2bf(ts[hr][d4 + 0]); o.y = f2bf(ts[hr][d4 + 1]);
        o.z = f2bf(ts[hr][d4 + 2]); o.w = f2bf(ts[hr][d4 + 3]);
        *(us4*)(dst + (size_t)hr * D_N + d4) = o;
    }
}

// ---------------- grouped fused GEMM: 288x256 tile, T3+T4+T5 conjunction --------------
// 256 items (32 M-tiles x 8 nc), 1 block/CU, 512 thr (8 waves 2Mx4N, wave tile 144x64).
// BK=32 half-steps, 4-buffer rotation: stage(t+2) issued during step t; wait at top of
// step t is COUNTED vmcnt(4|5) (= stage(t+1) in flight) -- never 0 in the main loop
// (m218: counted-vs-drain0 = +38-73% ON the phase-interleaved structure).
// Per half-step: 2 phases {ds_reads | stage issue | lgkm0+schedbar | prio1 MFMA prio0 | bar}.
// XOR swizzle on 64-B rows: chunk = l4 ^ (row&3) -> 2 lanes/bank (free, m136).
__global__ __launch_bounds__(512, 2) void gemm_kernel(
                            const u16* __restrict__ xbf,
                            const u16* __restrict__ w1t,
                            const float* __restrict__ b1,
                            const float* __restrict__ w2,
                            const u32* __restrict__ idxl,
                            const u32* __restrict__ counts,
                            float* __restrict__ llp) {
    extern __shared__ char lds[];
    int tid = threadIdx.x;
    int lane = tid & 63, w = tid >> 6;
    int wm = w >> 2, wn = w & 3;
    int wmbase = wm * 144;
    int l15 = lane & 15, l4 = lane >> 4;

    u32* ro = (u32*)(lds + RO_OFF);
    float* pll = (float*)(lds + PLL_OFF);

    // total work items (uniform across block)
    int ntiles = 0;
#pragma unroll
    for (int kk = 0; kk < K_N; ++kk)
        ntiles += ((int)counts[kk * 32] + BM - 1) / BM;
    int total = ntiles * 8;

    // per-lane fragment base offsets: row lines are 64 B (4 chunks), chunk = l4 ^ (row&3)
    int swz = l15 & 3;
    u32 aBase = (u32)((wmbase + l15) * 64 + ((l4 ^ swz) << 4));
    u32 bBase = (u32)(ABYTES_HS + (wn * 64 + l15) * 64 + ((l4 ^ swz) << 4));

    const char* xb = (const char*)xbf;
    const char* wb = (const char*)w1t;

#define BAR() do { asm volatile("" ::: "memory"); __builtin_amdgcn_s_barrier(); \
                   asm volatile("" ::: "memory"); } while (0)
#define LGKM0_PIN() do { asm volatile("s_waitcnt lgkmcnt(0)" ::: "memory"); \
                         __builtin_amdgcn_sched_barrier(0); } while (0)

    for (int item = blockIdx.x; item < total; item += NBLK) {
        int tile = item >> 3, nc = item & 7;   // nc=item&7: XCD g sees one nc -> B L2-res
        int k = 0, mt = 0, nt = 0;
#pragma unroll
        for (int kk = 0; kk < K_N; ++kk) {
            int c = (int)counts[kk * 32];
            int t = (c + BM - 1) / BM;
            if (tile >= nt && tile < nt + t) { k = kk; mt = tile - nt; }
            nt += t;
        }
        int cnt = (int)counts[k * 32];
        int rows = cnt - mt * BM; if (rows > BM) rows = BM;
        int h0 = nc * BN;

        if (tid < BM) {
            int m = mt * BM + tid;
            int mm = m < cnt ? m : cnt - 1;
            ro[tid] = idxl[(size_t)k * B_N + mm] * (u32)(D_N * 2);
        }
        __syncthreads();

        // staging source offsets (pre-swizzled: linear LDS dest + swizzled read)
        u32 srcA[3], srcB[2];
#pragma unroll
        for (int i = 0; i < 2; ++i) {
            int c = i * 512 + tid; int r = c >> 2, j = c & 3;
            srcA[i] = ro[r] + ((u32)(j ^ (r & 3)) << 4);
        }
        if (w < 2) {   // remainder: rows 256..287, threads 0..127
            int c = 1024 + tid; int r = c >> 2, j = c & 3;
            srcA[2] = ro[r] + ((u32)(j ^ (r & 3)) << 4);
        } else srcA[2] = 0;
#pragma unroll
        for (int i = 0; i < 2; ++i) {
            int c = i * 512 + tid; int r = c >> 2, j = c & 3;
            srcB[i] = ((u32)(k * H_N + h0 + r) << 11) + ((u32)(j ^ (r & 3)) << 4);
        }

        float4v acc[9][4];
#pragma unroll
        for (int mf = 0; mf < 9; ++mf)
#pragma unroll
            for (int nf = 0; nf < 4; ++nf)
                acc[mf][nf] = (float4v){0.f, 0.f, 0.f, 0.f};

        auto stageA = [&](int tt) {
            char* Bp = lds + (tt & 3) * HSB;
            u32 d = (u32)(tt << 6);
            async_copy16(Bp + tid * 16,         xb + srcA[0] + d);
            async_copy16(Bp + 8192 + tid * 16,  xb + srcA[1] + d);
            if (w < 2)
                async_copy16(Bp + 16384 + tid * 16, xb + srcA[2] + d);
        };
        auto stageB = [&](int tt) {
            char* Bp = lds + (tt & 3) * HSB + ABYTES_HS;
            u32 d = (u32)(tt << 6);
            async_copy16(Bp + tid * 16,         wb + srcB[0] + d);
            async_copy16(Bp + 8192 + tid * 16,  wb + srcB[1] + d);
        };

        // prologue: stage half-steps 0 and 1 (2 in flight)
        stageA(0); stageB(0);
        stageA(1); stageB(1);

        for (int t = 0; t < 32; ++t) {
            const char* buf = lds + (t & 3) * HSB;
            bool pre = (t < 30);
            // counted gate: stage(t) landed, stage(t+1) stays in flight (T4)
            if (t < 31) {
                if (w < 2) asm volatile("s_waitcnt vmcnt(5)" ::: "memory");
                else       asm volatile("s_waitcnt vmcnt(4)" ::: "memory");
            } else {
                asm volatile("s_waitcnt vmcnt(0)" ::: "memory");
            }
            BAR();

            short8 a[9], bC[4];
            // ---- P0: read B + A(mf0-4); issue stage-A(t+2); 20 MFMA
#pragma unroll
            for (int nf = 0; nf < 4; ++nf)
                bC[nf] = *(const short8*)(buf + bBase + nf * 1024);
#pragma unroll
            for (int mf = 0; mf < 5; ++mf)
                a[mf] = *(const short8*)(buf + aBase + mf * 1024);
            if (pre) stageA(t + 2);
            LGKM0_PIN();
            __builtin_amdgcn_s_setprio(1);
#pragma unroll
            for (int mf = 0; mf < 5; ++mf) {
                if (wmbase + mf * 16 < rows) {
#pragma unroll
                    for (int nf = 0; nf < 4; ++nf)
                        acc[mf][nf] = __builtin_amdgcn_mfma_f32_16x16x32_bf16(
                            a[mf], bC[nf], acc[mf][nf], 0, 0, 0);
                }
            }
            __builtin_amdgcn_s_setprio(0);
            BAR();

            // ---- P1: read A(mf5-8); issue stage-B(t+2); 16 MFMA
#pragma unroll
            for (int mf = 5; mf < 9; ++mf)
                a[mf] = *(const short8*)(buf + aBase + mf * 1024);
            if (pre) stageB(t + 2);
            LGKM0_PIN();
            __builtin_amdgcn_s_setprio(1);
#pragma unroll
            for (int mf = 5; mf < 9; ++mf) {
                if (wmbase + mf * 16 < rows) {
#pragma unroll
                    for (int nf = 0; nf < 4; ++nf)
                        acc[mf][nf] = __builtin_amdgcn_mfma_f32_16x16x32_bf16(
                            a[mf], bC[nf], acc[mf][nf], 0, 0, 0);
                }
            }
            __builtin_amdgcn_s_setprio(0);
        }

        // epilogue: tanh + W2 weighted row-sum
        float w2v[4], b1v[4];
#pragma unroll
        for (int nf = 0; nf < 4; ++nf) {
            int h = h0 + wn * 64 + nf * 16 + l15;
            w2v[nf] = w2[k * H_N + h];
            b1v[nf] = b1[k * H_N + h];
        }
#pragma unroll
        for (int mf = 0; mf < 9; ++mf) {
            float rs[4] = {0.f, 0.f, 0.f, 0.f};
#pragma unroll
            for (int nf = 0; nf < 4; ++nf) {
#pragma unroll
                for (int r = 0; r < 4; ++r)
                    rs[r] += fast_tanh(acc[mf][nf][r] + b1v[nf]) * w2v[nf];
            }
#pragma unroll
            for (int r = 0; r < 4; ++r) {
                float v = rs[r];
                v += __shfl_xor(v, 8);
                v += __shfl_xor(v, 4);
                v += __shfl_xor(v, 2);
                v += __shfl_xor(v, 1);
                if (l15 == 0) pll[wn * 288 + wmbase + mf * 16 + l4 * 4 + r] = v;
            }
        }
        __syncthreads();
        if (tid < BM) {
            int m = mt * BM + tid;
            if (m < cnt) {
                u32 b = idxl[(size_t)k * B_N + m];
                llp[(size_t)nc * B_N + b] = pll[tid] + pll[288 + tid] + pll[576 + tid] + pll[864 + tid];
            }
        }
        __syncthreads();   // pll/ro safe for next item
    }
#undef BAR
#undef LGKM0_PIN
}

// ---------------- combine partials + b2 ----------------
__global__ void combine_kernel(const float* __restrict__ llp,
                               const int* __restrict__ cluster,
                               const float* __restrict__ b2,
                               float* __restrict__ out) {
    int b = blockIdx.x * 256 + threadIdx.x;
    float s = b2[cluster[b]];
#pragma unroll
    for (int nc = 0; nc < 8; ++nc) s += llp[(size_t)nc * B_N + b];
    out[b] = s;
}

extern "C" void kernel_launch(void* const* d_in, const int* in_sizes, int n_in,
                              void* d_out, int out_size, void* d_ws, size_t ws_size,
                              hipStream_t stream) {
    const float* x    = (const float*)d_in[0];
    const float* cent = (const float*)d_in[1];
    const float* W1   = (const float*)d_in[2];
    const float* b1   = (const float*)d_in[3];
    const float* W2   = (const float*)d_in[4];
    const float* b2   = (const float*)d_in[5];
    float* out = (float*)d_out;

    char* ws = (char*)d_ws;
    u16* xbf     = (u16*)(ws + 0);                 // 16 MB
    u16* w1t     = (u16*)(ws + 16777216);          // 32 MB
    u32* counts  = (u32*)(ws + 50331648);          // 8 strided u32 (1 KB pad)
    int* cluster = (int*)(ws + 50332672);          // 32 KB
    u32* idxl    = (u32*)(ws + 50365440);          // 256 KB
    float* llp   = (float*)(ws + 50627584);        // 256 KB

    (void)hipFuncSetAttribute((const void*)gemm_kernel,
                              hipFuncAttributeMaxDynamicSharedMemorySize, GEMM_LDS);

    hipLaunchKernelGGL(route_kernel, dim3(B_N / 4), dim3(256), 0, stream,
                       x, cent, xbf, cluster, counts);
    hipLaunchKernelGGL(scatter_kernel, dim3(32), dim3(256), 0, stream,
                       cluster, counts, idxl);
    hipLaunchKernelGGL(w1t_kernel, dim3(H_N / 64, D_N / 64, K_N), dim3(256), 0, stream,
                       W1, w1t);
    hipLaunchKernelGGL(gemm_kernel, dim3(NBLK), dim3(512), GEMM_LDS, stream,
                       xbf, w1t, b1, W2, idxl, counts, llp);
    hipLaunchKernelGGL(combine_kernel, dim3(B_N / 256), dim3(256), 0, stream,
                       llp, cluster, b2, out);
}

// Round 7
// 104.638 us; speedup vs baseline: 1.0623x; 1.0623x over previous
//
#include <hip/hip_runtime.h>
#include <hip/hip_bf16.h>
#include <stdint.h>

#define B_N 8192
#define D_N 1024
#define K_N 8
#define H_N 2048

#define BM 288
#define BN 256
#define NBLK 256
// Half-step (BK=32) buffers: A 288x32x2 = 18432 B + B 256x32x2 = 16384 B = 34816 B.
// 4-buffer rotation: 4 x 34816 = 139264.
//   ro=139264(1152) pll=140416(4608)  total 145024 (<=163840), 1 block/CU.
#define ABYTES_HS 18432
#define HSB 34816
#define RO_OFF 139264
#define PLL_OFF 140416
#define GEMM_LDS 145024

typedef unsigned int u32;
typedef unsigned short u16;
typedef __attribute__((ext_vector_type(8))) short short8;
typedef __attribute__((ext_vector_type(4))) float float4v;

struct __align__(8) us4 { u16 x, y, z, w; };

__device__ __forceinline__ u16 f2bf(float f) {
    union { float f; u32 u; } v; v.f = f;
    u32 u = v.u;
    u32 r = (u + 0x7fffu + ((u >> 16) & 1u)) >> 16;
    return (u16)r;
}

__device__ __forceinline__ float fast_tanh(float x) {
    float t = __expf(2.0f * x);
    return 1.0f - 2.0f * __builtin_amdgcn_rcpf(t + 1.0f);
}

__device__ __forceinline__ void async_copy16(void* lds, const void* g) {
    __builtin_amdgcn_global_load_lds(
        (const __attribute__((address_space(1))) void*)g,
        (__attribute__((address_space(3))) void*)lds, 16, 0, 0);
}

// ---------------- routing: f64 argmin + x->bf16 (NO atomics) ----------------
__global__ void route_kernel(const float* __restrict__ x,
                             const float* __restrict__ cent,
                             u16* __restrict__ xbf,
                             int* __restrict__ cluster,
                             u32* __restrict__ counts) {
    int tid = threadIdx.x;
    if (blockIdx.x == 0 && tid < K_N) counts[tid * 32] = 0;  // zero strided counters
    int wave = tid >> 6, lane = tid & 63;
    int b = blockIdx.x * 4 + wave;
    const float* xr = x + (size_t)b * D_N;

    float4 xv[4];
#pragma unroll
    for (int i = 0; i < 4; ++i)
        xv[i] = *(const float4*)(xr + i * 256 + lane * 4);

#pragma unroll
    for (int i = 0; i < 4; ++i) {
        us4 o;
        o.x = f2bf(xv[i].x); o.y = f2bf(xv[i].y);
        o.z = f2bf(xv[i].z); o.w = f2bf(xv[i].w);
        *(us4*)(xbf + (size_t)b * D_N + i * 256 + lane * 4) = o;
    }

    double acc[K_N];
#pragma unroll
    for (int k = 0; k < K_N; ++k) {
        const float* cr = cent + k * D_N;
        double s = 0.0;
#pragma unroll
        for (int i = 0; i < 4; ++i) {
            float4 cv = *(const float4*)(cr + i * 256 + lane * 4);
            double d0 = (double)xv[i].x - (double)cv.x; s += d0 * d0;
            double d1 = (double)xv[i].y - (double)cv.y; s += d1 * d1;
            double d2 = (double)xv[i].z - (double)cv.z; s += d2 * d2;
            double d3 = (double)xv[i].w - (double)cv.w; s += d3 * d3;
        }
        acc[k] = s;
    }
#pragma unroll
    for (int k = 0; k < K_N; ++k) {
        double v = acc[k];
        for (int off = 32; off; off >>= 1) v += __shfl_down(v, off);
        acc[k] = v;
    }
    if (lane == 0) {
        int best = 0; double bv = acc[0];
#pragma unroll
        for (int k = 1; k < K_N; ++k)
            if (acc[k] < bv) { bv = acc[k]; best = k; }
        cluster[b] = best;
    }
}

// ---------------- parallel binning: 32 blocks, ballot-rank + block reserve ----------------
__global__ void scatter_kernel(const int* __restrict__ cluster,
                               u32* __restrict__ counts,
                               u32* __restrict__ idxl) {
    __shared__ u32 wcnt[4][K_N];
    __shared__ u32 gb[K_N];
    int tid = threadIdx.x;
    int b = blockIdx.x * 256 + tid;
    int lane = tid & 63, wid = tid >> 6;
    int cl = cluster[b];
    unsigned long long lower = (1ull << lane) - 1ull;
    u32 rank = 0;
#pragma unroll
    for (int k = 0; k < K_N; ++k) {
        unsigned long long mk = __ballot(cl == k);
        if (k == cl) rank = (u32)__popcll(mk & lower);
        if (lane == 0) wcnt[wid][k] = (u32)__popcll(mk);
    }
    __syncthreads();
    if (tid < K_N) {
        u32 tot = wcnt[0][tid] + wcnt[1][tid] + wcnt[2][tid] + wcnt[3][tid];
        gb[tid] = atomicAdd(&counts[tid * 32], tot);   // reserve range (order-free)
    }
    __syncthreads();
    u32 woff = 0;
    if (wid > 0) woff += wcnt[0][cl];
    if (wid > 1) woff += wcnt[1][cl];
    if (wid > 2) woff += wcnt[2][cl];
    idxl[(size_t)cl * B_N + gb[cl] + woff + rank] = (u32)b;
}

// ---------------- W1[k,d,h] f32 -> W1t[k,h,d] bf16 (vectorized) ----------------
__global__ void w1t_kernel(const float* __restrict__ w1, u16* __restrict__ w1t) {
    __shared__ float ts[64][65];
    int tid = threadIdx.x;
    int h0 = blockIdx.x * 64, d0 = blockIdx.y * 64, k = blockIdx.z;
    const float* src = w1 + ((size_t)k * D_N + d0) * H_N + h0;
#pragma unroll
    for (int i = 0; i < 4; ++i) {
        int q = i * 256 + tid;
        int r = q >> 4, c4 = (q & 15) * 4;          // d-row, h-col4
        float4 v = *(const float4*)(src + (size_t)r * H_N + c4);
        ts[c4 + 0][r] = v.x; ts[c4 + 1][r] = v.y;
        ts[c4 + 2][r] = v.z; ts[c4 + 3][r] = v.w;
    }
    __syncthreads();
    u16* dst = w1t + ((size_t)k * H_N + h0) * D_N + d0;
#pragma unroll
    for (int i = 0; i < 4; ++i) {
        int q = i * 256 + tid;
        int hr = q >> 4, d4 = (q & 15) * 4;         // h-row, d-col4
        us4 o;
        o.x = f2bf(ts[hr][d4 + 0]); o.y = f2bf(ts[hr][d4 + 1]);
        o.z = f2bf(ts[hr][d4 + 2]); o.w = f2bf(ts[hr][d4 + 3]);
        *(us4*)(dst + (size_t)hr * D_N + d4) = o;
    }
}

// ---------------- grouped fused GEMM: 288x256, BK=32 4-buffer, counted-vmcnt ----------
// R6 skeleton minus its two measured bugs:
//  (1) paired-row swizzle (R1's, measured 0 conflicts): rows 2r,2r+1 share a 128-B
//      line; 16B slot = ((row&1)*4 + kchunk) ^ ((row>>1)&7).
//  (2) NO lgkmcnt(0) pin: plain C++ ds reads -> compiler emits counted lgkm, so
//      MFMA starts when its frags land and remaining reads drain under MFMA.
// One barrier per half-step (32/item). Counted vmcnt(5|4) gate: stage(t+1) stays
// in flight across the gate (never drains to 0 in the main loop -- m218 lever).
__global__ __launch_bounds__(512, 2) void gemm_kernel(
                            const u16* __restrict__ xbf,
                            const u16* __restrict__ w1t,
                            const float* __restrict__ b1,
                            const float* __restrict__ w2,
                            const u32* __restrict__ idxl,
                            const u32* __restrict__ counts,
                            float* __restrict__ llp) {
    extern __shared__ char lds[];
    int tid = threadIdx.x;
    int lane = tid & 63, w = tid >> 6;
    int wm = w >> 2, wn = w & 3;
    int wmbase = wm * 144;
    int l15 = lane & 15, l4 = lane >> 4;

    u32* ro = (u32*)(lds + RO_OFF);
    float* pll = (float*)(lds + PLL_OFF);

    // total work items (uniform across block)
    int ntiles = 0;
#pragma unroll
    for (int kk = 0; kk < K_N; ++kk)
        ntiles += ((int)counts[kk * 32] + BM - 1) / BM;
    int total = ntiles * 8;

    // paired-row fragment offset: row = rbase + l15 (rbase % 16 == 0), kchunk = l4
    // addr = rbase*64 + (l15>>1)*128 + ((((l15&1)<<2)|l4) ^ ((l15>>1)&7))*16
    u32 frOff = (u32)(((l15 >> 1) << 7) |
                      (((((l15 & 1) << 2) | l4) ^ ((l15 >> 1) & 7)) << 4));
    u32 aBase = (u32)(wmbase * 64) + frOff;                    // + mf*1024
    u32 bBase = (u32)(ABYTES_HS + wn * 4096) + frOff;          // + nf*1024

    const char* xb = (const char*)xbf;
    const char* wb = (const char*)w1t;

#define BAR() do { asm volatile("" ::: "memory"); __builtin_amdgcn_s_barrier(); \
                   asm volatile("" ::: "memory"); } while (0)

    for (int item = blockIdx.x; item < total; item += NBLK) {
        int tile = item >> 3, nc = item & 7;   // nc=item&7: XCD g sees one nc -> B L2-res
        int k = 0, mt = 0, nt = 0;
#pragma unroll
        for (int kk = 0; kk < K_N; ++kk) {
            int c = (int)counts[kk * 32];
            int t = (c + BM - 1) / BM;
            if (tile >= nt && tile < nt + t) { k = kk; mt = tile - nt; }
            nt += t;
        }
        int cnt = (int)counts[k * 32];
        int rows = cnt - mt * BM; if (rows > BM) rows = BM;
        int h0 = nc * BN;

        if (tid < BM) {
            int m = mt * BM + tid;
            int mm = m < cnt ? m : cnt - 1;
            ro[tid] = idxl[(size_t)k * B_N + mm] * (u32)(D_N * 2);
        }
        __syncthreads();

        // staging source offsets, paired-row layout (linear LDS dest = chunk*16):
        // chunk c: row2=c>>3, s=c&7, u=s^(row2&7) -> row=2*row2+(u>>2), kchunk=u&3
        u32 srcA[3], srcB[2];
#pragma unroll
        for (int i = 0; i < 2; ++i) {
            int c = i * 512 + tid;
            int row2 = c >> 3, u = (c & 7) ^ (row2 & 7);
            srcA[i] = ro[row2 * 2 + (u >> 2)] + (u32)((u & 3) << 4);
        }
        if (w < 2) {   // remainder chunks 1024..1151 (rows 256..287)
            int c = 1024 + tid;
            int row2 = c >> 3, u = (c & 7) ^ (row2 & 7);
            srcA[2] = ro[row2 * 2 + (u >> 2)] + (u32)((u & 3) << 4);
        } else srcA[2] = 0;
#pragma unroll
        for (int i = 0; i < 2; ++i) {
            int c = i * 512 + tid;
            int row2 = c >> 3, u = (c & 7) ^ (row2 & 7);
            srcB[i] = ((u32)(k * H_N + h0 + row2 * 2 + (u >> 2)) << 11) + (u32)((u & 3) << 4);
        }

        float4v acc[9][4];
#pragma unroll
        for (int mf = 0; mf < 9; ++mf)
#pragma unroll
            for (int nf = 0; nf < 4; ++nf)
                acc[mf][nf] = (float4v){0.f, 0.f, 0.f, 0.f};

        auto stageAB = [&](int tt) {
            char* Bp = lds + (tt & 3) * HSB;
            u32 d = (u32)(tt << 6);
            async_copy16(Bp + tid * 16,         xb + srcA[0] + d);
            async_copy16(Bp + 8192 + tid * 16,  xb + srcA[1] + d);
            if (w < 2)
                async_copy16(Bp + 16384 + tid * 16, xb + srcA[2] + d);
            async_copy16(Bp + ABYTES_HS + tid * 16,        wb + srcB[0] + d);
            async_copy16(Bp + ABYTES_HS + 8192 + tid * 16, wb + srcB[1] + d);
        };

        // prologue: stage half-steps 0 and 1 (2 in flight)
        stageAB(0);
        stageAB(1);

        for (int t = 0; t < 32; ++t) {
            const char* buf = lds + (t & 3) * HSB;
            // counted gate: stage(t) landed; stage(t+1) (5|4 ops) stays in flight
            if (t < 31) {
                if (w < 2) asm volatile("s_waitcnt vmcnt(5)" ::: "memory");
                else       asm volatile("s_waitcnt vmcnt(4)" ::: "memory");
            } else {
                asm volatile("s_waitcnt vmcnt(0)" ::: "memory");
            }
            BAR();   // one barrier per half-step: buffer t ready for all waves

            short8 bC[4], a[9];
#pragma unroll
            for (int nf = 0; nf < 4; ++nf)
                bC[nf] = *(const short8*)(buf + bBase + nf * 1024);
#pragma unroll
            for (int mf = 0; mf < 9; ++mf)
                a[mf] = *(const short8*)(buf + aBase + mf * 1024);
            if (t < 30) stageAB(t + 2);
            // NO lgkm pin: compiler issues counted lgkmcnt per-frag; MFMA starts
            // as soon as its operands land, later reads drain under MFMA.
            __builtin_amdgcn_s_setprio(1);
#pragma unroll
            for (int mf = 0; mf < 9; ++mf) {
                if (wmbase + mf * 16 < rows) {
#pragma unroll
                    for (int nf = 0; nf < 4; ++nf)
                        acc[mf][nf] = __builtin_amdgcn_mfma_f32_16x16x32_bf16(
                            a[mf], bC[nf], acc[mf][nf], 0, 0, 0);
                }
            }
            __builtin_amdgcn_s_setprio(0);
        }

        // epilogue: tanh + W2 weighted row-sum
        float w2v[4], b1v[4];
#pragma unroll
        for (int nf = 0; nf < 4; ++nf) {
            int h = h0 + wn * 64 + nf * 16 + l15;
            w2v[nf] = w2[k * H_N + h];
            b1v[nf] = b1[k * H_N + h];
        }
#pragma unroll
        for (int mf = 0; mf < 9; ++mf) {
            float rs[4] = {0.f, 0.f, 0.f, 0.f};
#pragma unroll
            for (int nf = 0; nf < 4; ++nf) {
#pragma unroll
                for (int r = 0; r < 4; ++r)
                    rs[r] += fast_tanh(acc[mf][nf][r] + b1v[nf]) * w2v[nf];
            }
#pragma unroll
            for (int r = 0; r < 4; ++r) {
                float v = rs[r];
                v += __shfl_xor(v, 8);
                v += __shfl_xor(v, 4);
                v += __shfl_xor(v, 2);
                v += __shfl_xor(v, 1);
                if (l15 == 0) pll[wn * 288 + wmbase + mf * 16 + l4 * 4 + r] = v;
            }
        }
        __syncthreads();
        if (tid < BM) {
            int m = mt * BM + tid;
            if (m < cnt) {
                u32 b = idxl[(size_t)k * B_N + m];
                llp[(size_t)nc * B_N + b] = pll[tid] + pll[288 + tid] + pll[576 + tid] + pll[864 + tid];
            }
        }
        __syncthreads();   // pll/ro safe for next item
    }
#undef BAR
}

// ---------------- combine partials + b2 ----------------
__global__ void combine_kernel(const float* __restrict__ llp,
                               const int* __restrict__ cluster,
                               const float* __restrict__ b2,
                               float* __restrict__ out) {
    int b = blockIdx.x * 256 + threadIdx.x;
    float s = b2[cluster[b]];
#pragma unroll
    for (int nc = 0; nc < 8; ++nc) s += llp[(size_t)nc * B_N + b];
    out[b] = s;
}

extern "C" void kernel_launch(void* const* d_in, const int* in_sizes, int n_in,
                              void* d_out, int out_size, void* d_ws, size_t ws_size,
                              hipStream_t stream) {
    const float* x    = (const float*)d_in[0];
    const float* cent = (const float*)d_in[1];
    const float* W1   = (const float*)d_in[2];
    const float* b1   = (const float*)d_in[3];
    const float* W2   = (const float*)d_in[4];
    const float* b2   = (const float*)d_in[5];
    float* out = (float*)d_out;

    char* ws = (char*)d_ws;
    u16* xbf     = (u16*)(ws + 0);                 // 16 MB
    u16* w1t     = (u16*)(ws + 16777216);          // 32 MB
    u32* counts  = (u32*)(ws + 50331648);          // 8 strided u32 (1 KB pad)
    int* cluster = (int*)(ws + 50332672);          // 32 KB
    u32* idxl    = (u32*)(ws + 50365440);          // 256 KB
    float* llp   = (float*)(ws + 50627584);        // 256 KB

    (void)hipFuncSetAttribute((const void*)gemm_kernel,
                              hipFuncAttributeMaxDynamicSharedMemorySize, GEMM_LDS);

    hipLaunchKernelGGL(route_kernel, dim3(B_N / 4), dim3(256), 0, stream,
                       x, cent, xbf, cluster, counts);
    hipLaunchKernelGGL(scatter_kernel, dim3(32), dim3(256), 0, stream,
                       cluster, counts, idxl);
    hipLaunchKernelGGL(w1t_kernel, dim3(H_N / 64, D_N / 64, K_N), dim3(256), 0, stream,
                       W1, w1t);
    hipLaunchKernelGGL(gemm_kernel, dim3(NBLK), dim3(512), GEMM_LDS, stream,
                       xbf, w1t, b1, W2, idxl, counts, llp);
    hipLaunchKernelGGL(combine_kernel, dim3(B_N / 256), dim3(256), 0, stream,
                       llp, cluster, b2, out);
}